// Round 1
// baseline (1713.058 us; speedup 1.0000x reference)
//
#include <hip/hip_runtime.h>
#include <stdint.h>

// Problem constants (fixed by reference: B=4, S=2048, IN=4096, OUT=16384)
#define M_ROWS 8192     // B*S
#define N_COLS 16384    // OUT
#define K_ELEMS 4096    // IN
#define KW 128          // K in u32 words (4096/32)
#define LDS_STRIDE 20   // 16 payload words + 4 pad: 16B-aligned rows, <=2-way bank conflict

// ---------------- sign-pack kernels (ballot-based, coalesced) ----------------
// bit = 1  <=>  value < 0  <=>  binarized value = -1
__global__ void pack_x_kernel(const float* __restrict__ x,
                              uint64_t* __restrict__ out, int n) {
    int stride = gridDim.x * blockDim.x;
    for (int idx = blockIdx.x * blockDim.x + threadIdx.x; idx < n; idx += stride) {
        float v = x[idx];
        uint64_t mask = __ballot(v < 0.0f);
        if ((threadIdx.x & 63) == 0) out[idx >> 6] = mask;
    }
}

__global__ void pack_w_kernel(const float* __restrict__ w,
                              const float* __restrict__ thr,
                              uint64_t* __restrict__ out, int n) {
    int stride = gridDim.x * blockDim.x;
    for (int idx = blockIdx.x * blockDim.x + threadIdx.x; idx < n; idx += stride) {
        float v = w[idx] - thr[idx >> 12];   // row = idx / 4096
        uint64_t mask = __ballot(v < 0.0f);
        if ((threadIdx.x & 63) == 0) out[idx >> 6] = mask;
    }
}

// ---------------- binary GEMM: C = (K - 2*popc(a XOR b)) * scale ----------------
// 128x128 block tile, 256 threads, 8x8 per thread (interleaved by 16).
__launch_bounds__(256)
__global__ void bgemm_kernel(const uint32_t* __restrict__ A,   // [M][KW] packed
                             const uint32_t* __restrict__ B,   // [N][KW] packed
                             const float* __restrict__ shift,
                             float* __restrict__ out) {
    __shared__ uint32_t As[128 * LDS_STRIDE];
    __shared__ uint32_t Bs[128 * LDS_STRIDE];

    const int tid = threadIdx.x;
    const int tx = tid & 15;        // column group
    const int ty = tid >> 4;        // row group
    const int bm = blockIdx.y * 128;
    const int bn = blockIdx.x * 128;

    uint32_t acc[8][8];
    #pragma unroll
    for (int i = 0; i < 8; ++i)
        #pragma unroll
        for (int j = 0; j < 8; ++j) acc[i][j] = 0u;

    for (int kb = 0; kb < KW; kb += 16) {
        // ---- stage 128x16-word tiles of A and B into LDS ----
        #pragma unroll
        for (int l = 0; l < 2; ++l) {
            int li = tid + 256 * l;          // 0..511
            int row = li >> 2;               // 0..127
            int g = li & 3;                  // uint4 group within row
            const uint4 av = *(const uint4*)&A[(size_t)(bm + row) * KW + kb + g * 4];
            const uint4 bv = *(const uint4*)&B[(size_t)(bn + row) * KW + kb + g * 4];
            *(uint4*)&As[row * LDS_STRIDE + g * 4] = av;
            *(uint4*)&Bs[row * LDS_STRIDE + g * 4] = bv;
        }
        __syncthreads();

        // ---- compute: 4 k-groups of 4 words each ----
        #pragma unroll
        for (int g = 0; g < 4; ++g) {
            uint4 a[8], b[8];
            #pragma unroll
            for (int r = 0; r < 8; ++r)
                a[r] = *(const uint4*)&As[(ty + 16 * r) * LDS_STRIDE + g * 4];
            #pragma unroll
            for (int c = 0; c < 8; ++c)
                b[c] = *(const uint4*)&Bs[(tx + 16 * c) * LDS_STRIDE + g * 4];
            #pragma unroll
            for (int r = 0; r < 8; ++r) {
                #pragma unroll
                for (int c = 0; c < 8; ++c) {
                    acc[r][c] += __popc(a[r].x ^ b[c].x);
                    acc[r][c] += __popc(a[r].y ^ b[c].y);
                    acc[r][c] += __popc(a[r].z ^ b[c].z);
                    acc[r][c] += __popc(a[r].w ^ b[c].w);
                }
            }
        }
        __syncthreads();
    }

    // ---- epilogue: value = (4096 - 2*popc) * scale ----
    float sp = shift[0];
    float rr = rintf(fminf(fmaxf(sp, -8.0f), 0.0f));   // round-half-even, matches jnp.round
    float scale = exp2f(rr);                            // exact power of two
    float base = (float)K_ELEMS * scale;
    float m2s = -2.0f * scale;

    #pragma unroll
    for (int i = 0; i < 8; ++i) {
        size_t rowoff = (size_t)(bm + ty + 16 * i) * (size_t)N_COLS + (size_t)bn;
        #pragma unroll
        for (int j = 0; j < 8; ++j) {
            out[rowoff + tx + 16 * j] = fmaf(m2s, (float)acc[i][j], base);
        }
    }
}

extern "C" void kernel_launch(void* const* d_in, const int* in_sizes, int n_in,
                              void* d_out, int out_size, void* d_ws, size_t ws_size,
                              hipStream_t stream) {
    const float* x     = (const float*)d_in[0];   // [4,2048,4096] fp32
    const float* w     = (const float*)d_in[1];   // [16384,4096] fp32
    const float* thr   = (const float*)d_in[2];   // [16384,1] fp32
    const float* shift = (const float*)d_in[3];   // scalar fp32

    uint32_t* Apk = (uint32_t*)d_ws;                       // 4 MB
    uint32_t* Bpk = Apk + (size_t)M_ROWS * KW;             // 8 MB
    float* out = (float*)d_out;

    pack_x_kernel<<<2048, 256, 0, stream>>>(x, (uint64_t*)Apk, M_ROWS * K_ELEMS);
    pack_w_kernel<<<4096, 256, 0, stream>>>(w, thr, (uint64_t*)Bpk, N_COLS * K_ELEMS);

    dim3 grid(N_COLS / 128, M_ROWS / 128);   // (128, 64) = 8192 blocks
    bgemm_kernel<<<grid, 256, 0, stream>>>(Apk, Bpk, shift, out);
}

// Round 2
// 1593.755 us; speedup vs baseline: 1.0749x; 1.0749x over previous
//
#include <hip/hip_runtime.h>
#include <stdint.h>

// Problem constants (fixed by reference: B=4, S=2048, IN=4096, OUT=16384)
#define M_ROWS 8192     // B*S
#define N_COLS 16384    // OUT
#define K_ELEMS 4096    // IN
#define KW 128          // K in u32 words (4096/32)
#define LDS_STRIDE 20   // 16 payload words + 4 pad: 16B-aligned rows, <=2-way bank conflict

// ---------------- sign-pack kernels (float4 + ballot, K-permuted layout) ------
// bit = 1  <=>  value < 0  <=>  binarized value = -1.
// Within each 256-element K-group, bits are stored in ballot order:
// word layout [m0.lo, m0.hi, m1.lo, m1.hi, m2.lo, m2.hi, m3.lo, m3.hi] where
// m_c bit L = sign(elem 4L + c). Both A and B use the SAME permutation, and
// popc(a ^ b) is invariant under any shared K-permutation -> results exact.
__global__ void pack_x_kernel(const float4* __restrict__ x,
                              uint64_t* __restrict__ out, int nwaves) {
    int lane = threadIdx.x & 63;
    int gw = (blockIdx.x * blockDim.x + threadIdx.x) >> 6;
    int stride = (gridDim.x * blockDim.x) >> 6;
    for (int w = gw; w < nwaves; w += stride) {
        float4 v = x[(size_t)w * 64 + lane];
        uint64_t m0 = __ballot(v.x < 0.0f);
        uint64_t m1 = __ballot(v.y < 0.0f);
        uint64_t m2 = __ballot(v.z < 0.0f);
        uint64_t m3 = __ballot(v.w < 0.0f);
        uint64_t sel = (lane == 0) ? m0 : (lane == 1) ? m1 : (lane == 2) ? m2 : m3;
        if (lane < 4) out[(size_t)w * 4 + lane] = sel;
    }
}

__global__ void pack_w_kernel(const float4* __restrict__ wgt,
                              const float* __restrict__ thr,
                              uint64_t* __restrict__ out, int nwaves) {
    int lane = threadIdx.x & 63;
    int gw = (blockIdx.x * blockDim.x + threadIdx.x) >> 6;
    int stride = (gridDim.x * blockDim.x) >> 6;
    for (int w = gw; w < nwaves; w += stride) {
        size_t f4 = (size_t)w * 64 + lane;
        float t = thr[f4 >> 10];          // 1024 float4 per 4096-elem row
        float4 v = wgt[f4];
        uint64_t m0 = __ballot(v.x - t < 0.0f);
        uint64_t m1 = __ballot(v.y - t < 0.0f);
        uint64_t m2 = __ballot(v.z - t < 0.0f);
        uint64_t m3 = __ballot(v.w - t < 0.0f);
        uint64_t sel = (lane == 0) ? m0 : (lane == 1) ? m1 : (lane == 2) ? m2 : m3;
        if (lane < 4) out[(size_t)w * 4 + lane] = sel;
    }
}

// ---------------- binary GEMM: C = (K - 2*popc(a XOR b)) * scale ----------------
// 128x128 block tile, 256 threads, 8x8 per thread (interleaved by 16).
// __launch_bounds__(256,2): 256-VGPR budget so acc[64]+b[8] stay in arch VGPRs
// (plain launch_bounds made the compiler cap at 92 VGPR and round-trip the
// accumulators through AGPRs -> ~2x dynamic VALU instructions).
__launch_bounds__(256, 2)
__global__ void bgemm_kernel(const uint32_t* __restrict__ A,   // [M][KW] packed
                             const uint32_t* __restrict__ B,   // [N][KW] packed
                             const float* __restrict__ shift,
                             float* __restrict__ out) {
    __shared__ uint32_t As[128 * LDS_STRIDE];
    __shared__ uint32_t Bs[128 * LDS_STRIDE];

    const int tid = threadIdx.x;
    const int tx = tid & 15;        // column group
    const int ty = tid >> 4;        // row group
    const int bm = blockIdx.y * 128;
    const int bn = blockIdx.x * 128;

    // staging assignment: thread stages 2 uint4 groups per array
    const int r0 = tid >> 2, g0 = tid & 3;          // li = tid
    const int r1 = (tid + 256) >> 2, g1 = tid & 3;  // li = tid + 256

    uint32_t acc[8][8];
    #pragma unroll
    for (int i = 0; i < 8; ++i)
        #pragma unroll
        for (int j = 0; j < 8; ++j) acc[i][j] = 0u;

    // prefetch registers for the next k-stage
    uint4 pa0, pa1, pb0, pb1;
    pa0 = *(const uint4*)&A[(size_t)(bm + r0) * KW + 0 + g0 * 4];
    pa1 = *(const uint4*)&A[(size_t)(bm + r1) * KW + 0 + g1 * 4];
    pb0 = *(const uint4*)&B[(size_t)(bn + r0) * KW + 0 + g0 * 4];
    pb1 = *(const uint4*)&B[(size_t)(bn + r1) * KW + 0 + g1 * 4];

    for (int kb = 0; kb < KW; kb += 16) {
        *(uint4*)&As[r0 * LDS_STRIDE + g0 * 4] = pa0;
        *(uint4*)&As[r1 * LDS_STRIDE + g1 * 4] = pa1;
        *(uint4*)&Bs[r0 * LDS_STRIDE + g0 * 4] = pb0;
        *(uint4*)&Bs[r1 * LDS_STRIDE + g1 * 4] = pb1;
        __syncthreads();

        if (kb + 16 < KW) {   // issue next-stage loads before compute
            int kn = kb + 16;
            pa0 = *(const uint4*)&A[(size_t)(bm + r0) * KW + kn + g0 * 4];
            pa1 = *(const uint4*)&A[(size_t)(bm + r1) * KW + kn + g1 * 4];
            pb0 = *(const uint4*)&B[(size_t)(bn + r0) * KW + kn + g0 * 4];
            pb1 = *(const uint4*)&B[(size_t)(bn + r1) * KW + kn + g1 * 4];
        }

        // ---- compute: 4 k-groups of 4 words each ----
        #pragma unroll
        for (int g = 0; g < 4; ++g) {
            uint4 b[8];
            #pragma unroll
            for (int c = 0; c < 8; ++c)
                b[c] = *(const uint4*)&Bs[(tx + 16 * c) * LDS_STRIDE + g * 4];
            #pragma unroll
            for (int r = 0; r < 8; ++r) {
                uint4 a = *(const uint4*)&As[(ty + 16 * r) * LDS_STRIDE + g * 4];
                #pragma unroll
                for (int c = 0; c < 8; ++c) {
                    acc[r][c] += __popc(a.x ^ b[c].x);
                    acc[r][c] += __popc(a.y ^ b[c].y);
                    acc[r][c] += __popc(a.z ^ b[c].z);
                    acc[r][c] += __popc(a.w ^ b[c].w);
                }
            }
        }
        __syncthreads();
    }

    // ---- epilogue: value = (4096 - 2*popc) * scale ----
    float sp = shift[0];
    float rr = rintf(fminf(fmaxf(sp, -8.0f), 0.0f));   // round-half-even, matches jnp.round
    float scale = exp2f(rr);                            // exact power of two
    float base = (float)K_ELEMS * scale;
    float m2s = -2.0f * scale;

    #pragma unroll
    for (int i = 0; i < 8; ++i) {
        size_t rowoff = (size_t)(bm + ty + 16 * i) * (size_t)N_COLS + (size_t)bn;
        #pragma unroll
        for (int j = 0; j < 8; ++j) {
            out[rowoff + tx + 16 * j] = fmaf(m2s, (float)acc[i][j], base);
        }
    }
}

extern "C" void kernel_launch(void* const* d_in, const int* in_sizes, int n_in,
                              void* d_out, int out_size, void* d_ws, size_t ws_size,
                              hipStream_t stream) {
    const float* x     = (const float*)d_in[0];   // [4,2048,4096] fp32
    const float* w     = (const float*)d_in[1];   // [16384,4096] fp32
    const float* thr   = (const float*)d_in[2];   // [16384,1] fp32
    const float* shift = (const float*)d_in[3];   // scalar fp32

    uint32_t* Apk = (uint32_t*)d_ws;                       // 4 MB
    uint32_t* Bpk = Apk + (size_t)M_ROWS * KW;             // 8 MB
    float* out = (float*)d_out;

    // 256 elements per wave-iter
    pack_x_kernel<<<2048, 256, 0, stream>>>((const float4*)x, (uint64_t*)Apk,
                                            (M_ROWS * K_ELEMS) / 256);
    pack_w_kernel<<<4096, 256, 0, stream>>>((const float4*)w, thr, (uint64_t*)Bpk,
                                            (N_COLS * K_ELEMS) / 256);

    dim3 grid(N_COLS / 128, M_ROWS / 128);   // (128, 64) = 8192 blocks
    bgemm_kernel<<<grid, 256, 0, stream>>>(Apk, Bpk, shift, out);
}